// Round 3
// baseline (167.045 us; speedup 1.0000x reference)
//
#include <hip/hip_runtime.h>
#include <math.h>

#define THREADS 256
#define D 128
#define B1 64          // blocks for hist/scatter passes (scan kernel assumes 256*B1 == 16384)

// ---- pass 1a: per-block histogram of dst high byte (bucket id), digit-major out ----
__global__ void k_hist(const int* __restrict__ dst, int* __restrict__ hist_t, int E) {
    __shared__ int h[256];
    h[threadIdx.x] = 0;
    __syncthreads();
    int chunk = (E + gridDim.x - 1) / gridDim.x;
    int lo = blockIdx.x * chunk, hi = min(E, lo + chunk);
    for (int i = lo + threadIdx.x; i < hi; i += 256)
        atomicAdd(&h[dst[i] >> 8], 1);
    __syncthreads();
    hist_t[threadIdx.x * gridDim.x + blockIdx.x] = h[threadIdx.x];
}

// ---- pass 1b: exclusive scan of 16384-entry digit-major table (single block) ----
__global__ void k_scan16k(int* __restrict__ hist_t, int* __restrict__ bucket_start, int E) {
    __shared__ int tot[1024];
    int t = threadIdx.x;
    int base = t * 16;
    int v[16];
    int s = 0;
#pragma unroll
    for (int k = 0; k < 16; ++k) { v[k] = hist_t[base + k]; s += v[k]; }
    tot[t] = s;
    __syncthreads();
    for (int o = 1; o < 1024; o <<= 1) {
        int add = (t >= o) ? tot[t - o] : 0;
        __syncthreads();
        tot[t] += add;
        __syncthreads();
    }
    int run = tot[t] - s;  // exclusive
#pragma unroll
    for (int k = 0; k < 16; ++k) { int x = v[k]; hist_t[base + k] = run; run += x; }
    __syncthreads();
    if (t < 256) bucket_start[t] = (t * B1 < 16384) ? hist_t[t * B1] : E;
    if (t == 0) bucket_start[256] = E;
    // note: buckets >=196 are empty; bucket_start for them equals E anyway via scan
}

// ---- pass 1c: route edges into buckets (LDS cursors, no global atomics) ----
__global__ void k_scatter_pairs(const int* __restrict__ src, const int* __restrict__ dst,
                                const int* __restrict__ offs, unsigned* __restrict__ pairs, int E) {
    __shared__ int cur[256];
    cur[threadIdx.x] = offs[threadIdx.x * gridDim.x + blockIdx.x];
    __syncthreads();
    int chunk = (E + gridDim.x - 1) / gridDim.x;
    int lo = blockIdx.x * chunk, hi = min(E, lo + chunk);
    for (int i = lo + threadIdx.x; i < hi; i += 256) {
        int d = dst[i];
        int p = atomicAdd(&cur[d >> 8], 1);
        pairs[p] = ((unsigned)(d & 255) << 16) | (unsigned)src[i];
    }
}

// ---- pass 2: per-bucket CSR build; emits rowstart/deg/dinv and grouped csr ----
__global__ void k_bucket_csr(const unsigned* __restrict__ pairs, const int* __restrict__ bucket_start,
                             int* __restrict__ csr, int* __restrict__ rowstart,
                             int* __restrict__ deg, float* __restrict__ dinv, int N) {
    int b = blockIdx.x;
    int bstart = bucket_start[b], bend = bucket_start[b + 1];
    __shared__ int h[256];
    __shared__ int rs[256];
    int t = threadIdx.x;
    h[t] = 0;
    __syncthreads();
    for (int i = bstart + t; i < bend; i += 256)
        atomicAdd(&h[pairs[i] >> 16], 1);
    __syncthreads();
    int v = h[t];
    rs[t] = v;
    __syncthreads();
    for (int o = 1; o < 256; o <<= 1) {
        int add = (t >= o) ? rs[t - o] : 0;
        __syncthreads();
        rs[t] += add;
        __syncthreads();
    }
    int excl = rs[t] - v;
    int node = (b << 8) + t;
    if (node < N) {
        rowstart[node] = bstart + excl;
        deg[node] = v;
        dinv[node] = rsqrtf((float)(v + 1));
    }
    __syncthreads();
    h[t] = excl;           // reuse as scatter cursor (bucket-relative)
    __syncthreads();
    for (int i = bstart + t; i < bend; i += 256) {
        unsigned p = pairs[i];
        int pos = bstart + atomicAdd(&h[p >> 16], 1);
        csr[pos] = (int)(p & 0xFFFFu);
    }
}

// ---- W12 = W1 @ W2 (128x2), cvec = b1^T @ W2 (2) ----
__global__ void k_w12(const float* __restrict__ W1, const float* __restrict__ W2,
                      const float* __restrict__ b1, float* __restrict__ W12,
                      float* __restrict__ cvec) {
    int t = threadIdx.x;
    int k = t >> 1, c = t & 1;
    float acc = 0.f;
    for (int m = 0; m < D; ++m) acc += W1[k * D + m] * W2[m * 2 + c];
    W12[k * 2 + c] = acc;
    if (t < 2) {
        float s = 0.f;
        for (int m = 0; m < D; ++m) s += b1[m] * W2[m * 2 + t];
        cvec[t] = s;
    }
}

// ---- z = x @ W12, one wave per node row ----
__global__ void k_z(const float* __restrict__ x, const float* __restrict__ W12,
                    float2* __restrict__ z, int N) {
    int gid  = blockIdx.x * blockDim.x + threadIdx.x;
    int node = gid >> 6;
    int lane = threadIdx.x & 63;
    if (node >= N) return;
    float2 xv = *(const float2*)(x + (size_t)node * D + lane * 2);
    float4 wv = *(const float4*)(W12 + lane * 4);
    float p0 = xv.x * wv.x + xv.y * wv.z;
    float p1 = xv.x * wv.y + xv.y * wv.w;
#pragma unroll
    for (int o = 32; o > 0; o >>= 1) {
        p0 += __shfl_xor(p0, o);
        p1 += __shfl_xor(p1, o);
    }
    if (lane == 0) {
        float2 r; r.x = p0; r.y = p1;
        z[node] = r;
    }
}

// ---- Pass A (gather): a1 = Â z (incl self-loop), srow = Â 1 ----
__global__ void k_gatherA(const int* __restrict__ csr, const int* __restrict__ rowstart,
                          const int* __restrict__ deg, const float* __restrict__ dinv,
                          const float2* __restrict__ z, float2* __restrict__ a1,
                          float* __restrict__ srow, int N) {
    int g = blockIdx.x * blockDim.x + threadIdx.x;
    int node = g >> 4;
    int lane = threadIdx.x & 15;
    if (node >= N) return;
    int rs = rowstart[node], dg = deg[node];
    float acc0 = 0.f, acc1 = 0.f, sw = 0.f;
    for (int j = lane; j < dg; j += 16) {
        int s = csr[rs + j];
        float w = dinv[s];
        float2 zv = z[s];
        acc0 += w * zv.x; acc1 += w * zv.y; sw += w;
    }
#pragma unroll
    for (int o = 8; o > 0; o >>= 1) {
        acc0 += __shfl_xor(acc0, o);
        acc1 += __shfl_xor(acc1, o);
        sw   += __shfl_xor(sw, o);
    }
    if (lane == 0) {
        float wd = dinv[node], wd2 = wd * wd;
        float2 zv = z[node];
        float2 r;
        r.x = wd * acc0 + wd2 * zv.x;
        r.y = wd * acc1 + wd2 * zv.y;
        a1[node] = r;
        srow[node] = wd * sw + wd2;
    }
}

// ---- Pass B (gather) + rank-1 bias + gumbel softmax, fused ----
__global__ void k_gatherB(const int* __restrict__ csr, const int* __restrict__ rowstart,
                          const int* __restrict__ deg, const float* __restrict__ dinv,
                          const float2* __restrict__ a1, const float* __restrict__ srow,
                          const float* __restrict__ cvec, const float* __restrict__ b2,
                          const float2* __restrict__ noise, float2* __restrict__ out, int N) {
    int g = blockIdx.x * blockDim.x + threadIdx.x;
    int node = g >> 4;
    int lane = threadIdx.x & 15;
    if (node >= N) return;
    int rs = rowstart[node], dg = deg[node];
    float acc0 = 0.f, acc1 = 0.f;
    for (int j = lane; j < dg; j += 16) {
        int s = csr[rs + j];
        float w = dinv[s];
        float2 av = a1[s];
        acc0 += w * av.x; acc1 += w * av.y;
    }
#pragma unroll
    for (int o = 8; o > 0; o >>= 1) {
        acc0 += __shfl_xor(acc0, o);
        acc1 += __shfl_xor(acc1, o);
    }
    if (lane == 0) {
        const float EPS = 1e-9f;
        float wd = dinv[node], wd2 = wd * wd;
        float2 av = a1[node];
        float sr = srow[node];
        float l0 = wd * acc0 + wd2 * av.x + sr * cvec[0] + b2[0];
        float l1 = wd * acc1 + wd2 * av.y + sr * cvec[1] + b2[1];
        float2 nv = noise[node];
        float g0 = -logf(-logf(nv.x + EPS) + EPS);
        float g1 = -logf(-logf(nv.y + EPS) + EPS);
        float u0 = (l0 + g0) * 2.0f;
        float u1 = (l1 + g1) * 2.0f;
        float m = fmaxf(u0, u1);
        float e0 = __expf(u0 - m), e1 = __expf(u1 - m);
        float inv = 1.0f / (e0 + e1);
        float2 r; r.x = e0 * inv; r.y = e1 * inv;
        out[node] = r;
    }
}

extern "C" void kernel_launch(void* const* d_in, const int* in_sizes, int n_in,
                              void* d_out, int out_size, void* d_ws, size_t ws_size,
                              hipStream_t stream) {
    const float* x     = (const float*)d_in[0];
    const int*   ei    = (const int*)d_in[1];
    const float* W1    = (const float*)d_in[2];
    const float* b1    = (const float*)d_in[3];
    const float* W2    = (const float*)d_in[4];
    const float* b2    = (const float*)d_in[5];
    const float* noise = (const float*)d_in[6];
    float* out = (float*)d_out;

    const int N = in_sizes[0] / D;
    const int E = in_sizes[1] / 2;
    const int* src = ei;
    const int* dst = ei + E;

    // workspace carve (8B-aligned arrays first)
    char* p = (char*)d_ws;
    float* z        = (float*)p; p += (size_t)N * 8;
    float* a1       = (float*)p; p += (size_t)N * 8;
    unsigned* pairs = (unsigned*)p; p += (size_t)E * 4;
    int*   csr      = (int*)p;   p += (size_t)E * 4;
    int*   rowstart = (int*)p;   p += (size_t)N * 4;
    int*   deg      = (int*)p;   p += (size_t)N * 4;
    float* dinv     = (float*)p; p += (size_t)N * 4;
    float* srow     = (float*)p; p += (size_t)N * 4;
    int*   hist_t   = (int*)p;   p += 256 * B1 * 4;   // 16384 entries
    int*   bstart   = (int*)p;   p += 260 * 4;
    float* W12      = (float*)p; p += 256 * 4;
    float* cvec     = (float*)p; p += 16;

    int nbuckets = (N + 255) / 256;                  // 196
    int gZ  = (N + 3) / 4;                           // 64 lanes/node, 4 nodes/block
    int g16 = (N * 16 + THREADS - 1) / THREADS;      // 16 lanes/node

    k_hist<<<B1, 256, 0, stream>>>(dst, hist_t, E);
    k_scan16k<<<1, 1024, 0, stream>>>(hist_t, bstart, E);
    k_scatter_pairs<<<B1, 256, 0, stream>>>(src, dst, hist_t, pairs, E);
    k_w12<<<1, THREADS, 0, stream>>>(W1, W2, b1, W12, cvec);
    k_bucket_csr<<<nbuckets, 256, 0, stream>>>(pairs, bstart, csr, rowstart, deg, dinv, N);
    k_z<<<gZ, THREADS, 0, stream>>>(x, W12, (float2*)z, N);
    k_gatherA<<<g16, THREADS, 0, stream>>>(csr, rowstart, deg, dinv, (const float2*)z,
                                           (float2*)a1, srow, N);
    k_gatherB<<<g16, THREADS, 0, stream>>>(csr, rowstart, deg, dinv, (const float2*)a1,
                                           srow, cvec, b2, (const float2*)noise,
                                           (float2*)out, N);
}

// Round 4
// 91.401 us; speedup vs baseline: 1.8276x; 1.8276x over previous
//
#include <hip/hip_runtime.h>
#include <math.h>

#define THREADS 256
#define D 128
#define B1 512         // blocks for hist/scatter passes; table = 256*B1 entries

// ---- pass 1a: per-block histogram of dst high byte (bucket id), digit-major out ----
__global__ void k_hist(const int* __restrict__ dst, int* __restrict__ hist_t, int E) {
    __shared__ int h[256];
    h[threadIdx.x] = 0;
    __syncthreads();
    int chunk = (E + gridDim.x - 1) / gridDim.x;
    int lo = blockIdx.x * chunk, hi = min(E, lo + chunk);
    for (int i = lo + threadIdx.x; i < hi; i += 256)
        atomicAdd(&h[dst[i] >> 8], 1);
    __syncthreads();
    hist_t[threadIdx.x * gridDim.x + blockIdx.x] = h[threadIdx.x];
}

// ---- pass 1b: per-digit exclusive scan over its B1 block-counts; emits digit totals ----
__global__ void k_scan_digit(int* __restrict__ hist_t, int* __restrict__ dsum) {
    __shared__ int s[256];
    int d = blockIdx.x, t = threadIdx.x;
    int i0 = d * B1 + 2 * t;
    int a = hist_t[i0], b = hist_t[i0 + 1];
    s[t] = a + b;
    __syncthreads();
    for (int o = 1; o < 256; o <<= 1) {
        int add = (t >= o) ? s[t - o] : 0;
        __syncthreads();
        s[t] += add;
        __syncthreads();
    }
    int excl = s[t] - (a + b);
    hist_t[i0]     = excl;
    hist_t[i0 + 1] = excl + a;
    if (t == 255) dsum[d] = s[255];
}

// ---- pass 1c: exclusive scan of 256 digit totals -> bucket_start ----
__global__ void k_scan_bstart(const int* __restrict__ dsum, int* __restrict__ bstart, int E) {
    __shared__ int s[256];
    int t = threadIdx.x;
    int v = dsum[t];
    s[t] = v;
    __syncthreads();
    for (int o = 1; o < 256; o <<= 1) {
        int add = (t >= o) ? s[t - o] : 0;
        __syncthreads();
        s[t] += add;
        __syncthreads();
    }
    bstart[t] = s[t] - v;
    if (t == 255) bstart[256] = E;
}

// ---- pass 1d: route edges into buckets (LDS cursors, no global atomics) ----
__global__ void k_scatter_pairs(const int* __restrict__ src, const int* __restrict__ dst,
                                const int* __restrict__ hist_t, const int* __restrict__ bstart,
                                unsigned* __restrict__ pairs, int E) {
    __shared__ int cur[256];
    cur[threadIdx.x] = hist_t[threadIdx.x * gridDim.x + blockIdx.x] + bstart[threadIdx.x];
    __syncthreads();
    int chunk = (E + gridDim.x - 1) / gridDim.x;
    int lo = blockIdx.x * chunk, hi = min(E, lo + chunk);
    for (int i = lo + threadIdx.x; i < hi; i += 256) {
        int d = dst[i];
        int p = atomicAdd(&cur[d >> 8], 1);
        pairs[p] = ((unsigned)(d & 255) << 16) | (unsigned)src[i];
    }
}

// ---- pass 2: per-bucket CSR build; emits rowstart/deg/dinv and grouped csr ----
__global__ void k_bucket_csr(const unsigned* __restrict__ pairs, const int* __restrict__ bucket_start,
                             int* __restrict__ csr, int* __restrict__ rowstart,
                             int* __restrict__ deg, float* __restrict__ dinv, int N) {
    int b = blockIdx.x;
    int bs = bucket_start[b], be = bucket_start[b + 1];
    __shared__ int h[256];
    __shared__ int rs[256];
    int t = threadIdx.x;  // 0..1023
    if (t < 256) h[t] = 0;
    __syncthreads();
    for (int i = bs + t; i < be; i += 1024)
        atomicAdd(&h[pairs[i] >> 16], 1);
    __syncthreads();
    int v = 0;
    if (t < 256) { v = h[t]; rs[t] = v; }
    __syncthreads();
    for (int o = 1; o < 256; o <<= 1) {
        int add = (t < 256 && t >= o) ? rs[t - o] : 0;
        __syncthreads();
        if (t < 256) rs[t] += add;
        __syncthreads();
    }
    if (t < 256) {
        int excl = rs[t] - v;
        int node = (b << 8) + t;
        if (node < N) {
            rowstart[node] = bs + excl;
            deg[node] = v;
            dinv[node] = rsqrtf((float)(v + 1));
        }
        h[t] = excl;  // reuse as bucket-relative cursor
    }
    __syncthreads();
    for (int i = bs + t; i < be; i += 1024) {
        unsigned p = pairs[i];
        int pos = bs + atomicAdd(&h[p >> 16], 1);
        csr[pos] = (int)(p & 0xFFFFu);
    }
}

// ---- W12 = W1 @ W2 (128x2), cvec = b1^T @ W2 (2) ----
__global__ void k_w12(const float* __restrict__ W1, const float* __restrict__ W2,
                      const float* __restrict__ b1, float* __restrict__ W12,
                      float* __restrict__ cvec) {
    int t = threadIdx.x;
    int k = t >> 1, c = t & 1;
    float acc = 0.f;
    for (int m = 0; m < D; ++m) acc += W1[k * D + m] * W2[m * 2 + c];
    W12[k * 2 + c] = acc;
    if (t < 2) {
        float s = 0.f;
        for (int m = 0; m < D; ++m) s += b1[m] * W2[m * 2 + t];
        cvec[t] = s;
    }
}

// ---- z = x @ W12, one wave per node row ----
__global__ void k_z(const float* __restrict__ x, const float* __restrict__ W12,
                    float2* __restrict__ z, int N) {
    int gid  = blockIdx.x * blockDim.x + threadIdx.x;
    int node = gid >> 6;
    int lane = threadIdx.x & 63;
    if (node >= N) return;
    float2 xv = *(const float2*)(x + (size_t)node * D + lane * 2);
    float4 wv = *(const float4*)(W12 + lane * 4);
    float p0 = xv.x * wv.x + xv.y * wv.z;
    float p1 = xv.x * wv.y + xv.y * wv.w;
#pragma unroll
    for (int o = 32; o > 0; o >>= 1) {
        p0 += __shfl_xor(p0, o);
        p1 += __shfl_xor(p1, o);
    }
    if (lane == 0) {
        float2 r; r.x = p0; r.y = p1;
        z[node] = r;
    }
}

// ---- Pass A (gather): a1 = Â z (incl self-loop), srow = Â 1 ----
__global__ void k_gatherA(const int* __restrict__ csr, const int* __restrict__ rowstart,
                          const int* __restrict__ deg, const float* __restrict__ dinv,
                          const float2* __restrict__ z, float2* __restrict__ a1,
                          float* __restrict__ srow, int N) {
    int g = blockIdx.x * blockDim.x + threadIdx.x;
    int node = g >> 4;
    int lane = threadIdx.x & 15;
    if (node >= N) return;
    int rs = rowstart[node], dg = deg[node];
    float acc0 = 0.f, acc1 = 0.f, sw = 0.f;
    for (int j = lane; j < dg; j += 16) {
        int s = csr[rs + j];
        float w = dinv[s];
        float2 zv = z[s];
        acc0 += w * zv.x; acc1 += w * zv.y; sw += w;
    }
#pragma unroll
    for (int o = 8; o > 0; o >>= 1) {
        acc0 += __shfl_xor(acc0, o);
        acc1 += __shfl_xor(acc1, o);
        sw   += __shfl_xor(sw, o);
    }
    if (lane == 0) {
        float wd = dinv[node], wd2 = wd * wd;
        float2 zv = z[node];
        float2 r;
        r.x = wd * acc0 + wd2 * zv.x;
        r.y = wd * acc1 + wd2 * zv.y;
        a1[node] = r;
        srow[node] = wd * sw + wd2;
    }
}

// ---- Pass B (gather) + rank-1 bias + gumbel softmax, fused ----
__global__ void k_gatherB(const int* __restrict__ csr, const int* __restrict__ rowstart,
                          const int* __restrict__ deg, const float* __restrict__ dinv,
                          const float2* __restrict__ a1, const float* __restrict__ srow,
                          const float* __restrict__ cvec, const float* __restrict__ b2,
                          const float2* __restrict__ noise, float2* __restrict__ out, int N) {
    int g = blockIdx.x * blockDim.x + threadIdx.x;
    int node = g >> 4;
    int lane = threadIdx.x & 15;
    if (node >= N) return;
    int rs = rowstart[node], dg = deg[node];
    float acc0 = 0.f, acc1 = 0.f;
    for (int j = lane; j < dg; j += 16) {
        int s = csr[rs + j];
        float w = dinv[s];
        float2 av = a1[s];
        acc0 += w * av.x; acc1 += w * av.y;
    }
#pragma unroll
    for (int o = 8; o > 0; o >>= 1) {
        acc0 += __shfl_xor(acc0, o);
        acc1 += __shfl_xor(acc1, o);
    }
    if (lane == 0) {
        const float EPS = 1e-9f;
        float wd = dinv[node], wd2 = wd * wd;
        float2 av = a1[node];
        float sr = srow[node];
        float l0 = wd * acc0 + wd2 * av.x + sr * cvec[0] + b2[0];
        float l1 = wd * acc1 + wd2 * av.y + sr * cvec[1] + b2[1];
        float2 nv = noise[node];
        float g0 = -logf(-logf(nv.x + EPS) + EPS);
        float g1 = -logf(-logf(nv.y + EPS) + EPS);
        float u0 = (l0 + g0) * 2.0f;
        float u1 = (l1 + g1) * 2.0f;
        float m = fmaxf(u0, u1);
        float e0 = __expf(u0 - m), e1 = __expf(u1 - m);
        float inv = 1.0f / (e0 + e1);
        float2 r; r.x = e0 * inv; r.y = e1 * inv;
        out[node] = r;
    }
}

extern "C" void kernel_launch(void* const* d_in, const int* in_sizes, int n_in,
                              void* d_out, int out_size, void* d_ws, size_t ws_size,
                              hipStream_t stream) {
    const float* x     = (const float*)d_in[0];
    const int*   ei    = (const int*)d_in[1];
    const float* W1    = (const float*)d_in[2];
    const float* b1    = (const float*)d_in[3];
    const float* W2    = (const float*)d_in[4];
    const float* b2    = (const float*)d_in[5];
    const float* noise = (const float*)d_in[6];
    float* out = (float*)d_out;

    const int N = in_sizes[0] / D;
    const int E = in_sizes[1] / 2;
    const int* src = ei;
    const int* dst = ei + E;

    // workspace carve (8B-aligned arrays first)
    char* p = (char*)d_ws;
    float* z        = (float*)p; p += (size_t)N * 8;
    float* a1       = (float*)p; p += (size_t)N * 8;
    unsigned* pairs = (unsigned*)p; p += (size_t)E * 4;
    int*   csr      = (int*)p;   p += (size_t)E * 4;
    int*   rowstart = (int*)p;   p += (size_t)N * 4;
    int*   deg      = (int*)p;   p += (size_t)N * 4;
    float* dinv     = (float*)p; p += (size_t)N * 4;
    float* srow     = (float*)p; p += (size_t)N * 4;
    int*   hist_t   = (int*)p;   p += (size_t)256 * B1 * 4;  // 512 KB
    int*   dsum     = (int*)p;   p += 256 * 4;
    int*   bstart   = (int*)p;   p += 260 * 4;
    float* W12      = (float*)p; p += 256 * 4;
    float* cvec     = (float*)p; p += 16;

    int nbuckets = (N + 255) / 256;                  // 196
    int gZ  = (N + 3) / 4;                           // 64 lanes/node, 4 nodes/block
    int g16 = (N * 16 + THREADS - 1) / THREADS;      // 16 lanes/node

    k_hist<<<B1, 256, 0, stream>>>(dst, hist_t, E);
    k_scan_digit<<<256, 256, 0, stream>>>(hist_t, dsum);
    k_scan_bstart<<<1, 256, 0, stream>>>(dsum, bstart, E);
    k_scatter_pairs<<<B1, 256, 0, stream>>>(src, dst, hist_t, bstart, pairs, E);
    k_w12<<<1, THREADS, 0, stream>>>(W1, W2, b1, W12, cvec);
    k_bucket_csr<<<nbuckets, 1024, 0, stream>>>(pairs, bstart, csr, rowstart, deg, dinv, N);
    k_z<<<gZ, THREADS, 0, stream>>>(x, W12, (float2*)z, N);
    k_gatherA<<<g16, THREADS, 0, stream>>>(csr, rowstart, deg, dinv, (const float2*)z,
                                           (float2*)a1, srow, N);
    k_gatherB<<<g16, THREADS, 0, stream>>>(csr, rowstart, deg, dinv, (const float2*)a1,
                                           srow, cvec, b2, (const float2*)noise,
                                           (float2*)out, N);
}